// Round 1
// baseline (77197.919 us; speedup 1.0000x reference)
//
#include <hip/hip_runtime.h>
#include <hip/hip_fp16.h>

// LSTMTrajectoryEncoder on MI355X.
// Phase 1 (parallel): zx[t][c] = b_lstm[c] + leaky_relu(x[t]@W_in + b_in) @ Wi[:,c]
//   stored as f16 in ws, permuted so the scan kernel reads coalesced.
// Phase 2 (serial, 1 block): 65536-step LSTM recurrence, Wh in VGPRs,
//   h broadcast through LDS, quad-interleaved gates exchanged via shfl_xor,
//   one barrier per step. Final latent computed in-kernel.

#define TT   65536
#define DINN 128
#define HH   128
#define G4   512     // 4*H
#define NEG  0.01f
#define ROWS 16      // t-rows per GEMM block

// ---------------------------------------------------------------- GEMM kernel
__global__ __launch_bounds__(512) void zx_kernel(
    const float* __restrict__ x, const float* __restrict__ W_in,
    const float* __restrict__ b_in, const float* __restrict__ Wi,
    const float* __restrict__ b_lstm, __half* __restrict__ zx)
{
    __shared__ float xt[ROWS][DINN];
    __shared__ float xp[ROWS][DINN];
    const int tid = threadIdx.x;
    const int t0  = blockIdx.x * ROWS;

    // stage 0: load 16x128 x-tile (512 threads * float4)
    {
        const float4* src = (const float4*)(x + (size_t)t0 * DINN);
        ((float4*)&xt[0][0])[tid] = src[tid];
    }
    __syncthreads();

    // stage 1: xp = leaky(x@W_in + b_in); thread = (col c, row-group r0)
    {
        const int c  = tid & 127;
        const int r0 = tid >> 7;     // 0..3 -> rows r0, r0+4, r0+8, r0+12
        float a0 = b_in[c], a1 = a0, a2 = a0, a3 = a0;
        #pragma unroll
        for (int k4 = 0; k4 < DINN / 4; ++k4) {
            const float w0 = W_in[(k4*4+0)*DINN + c];
            const float w1 = W_in[(k4*4+1)*DINN + c];
            const float w2 = W_in[(k4*4+2)*DINN + c];
            const float w3 = W_in[(k4*4+3)*DINN + c];
            float4 v0 = *(const float4*)&xt[r0 +  0][k4*4];
            float4 v1 = *(const float4*)&xt[r0 +  4][k4*4];
            float4 v2 = *(const float4*)&xt[r0 +  8][k4*4];
            float4 v3 = *(const float4*)&xt[r0 + 12][k4*4];
            a0 += v0.x*w0 + v0.y*w1 + v0.z*w2 + v0.w*w3;
            a1 += v1.x*w0 + v1.y*w1 + v1.z*w2 + v1.w*w3;
            a2 += v2.x*w0 + v2.y*w1 + v2.z*w2 + v2.w*w3;
            a3 += v3.x*w0 + v3.y*w1 + v3.z*w2 + v3.w*w3;
        }
        xp[r0 +  0][c] = a0 >= 0.f ? a0 : NEG * a0;
        xp[r0 +  4][c] = a1 >= 0.f ? a1 : NEG * a1;
        xp[r0 +  8][c] = a2 >= 0.f ? a2 : NEG * a2;
        xp[r0 + 12][c] = a3 >= 0.f ? a3 : NEG * a3;
    }
    __syncthreads();

    // stage 2: zx = xp @ Wi + b_lstm; thread = column c2 (0..511), 16 rows
    {
        const int c2 = tid;
        float acc[ROWS];
        const float bl = b_lstm[c2];
        #pragma unroll
        for (int r = 0; r < ROWS; ++r) acc[r] = bl;
        #pragma unroll 4
        for (int k4 = 0; k4 < DINN / 4; ++k4) {
            const float w0 = Wi[(k4*4+0)*G4 + c2];
            const float w1 = Wi[(k4*4+1)*G4 + c2];
            const float w2 = Wi[(k4*4+2)*G4 + c2];
            const float w3 = Wi[(k4*4+3)*G4 + c2];
            #pragma unroll
            for (int r = 0; r < ROWS; ++r) {
                float4 a = *(const float4*)&xp[r][k4*4];
                acc[r] += a.x*w0 + a.y*w1 + a.z*w2 + a.w*w3;
            }
        }
        // permuted dest: scan thread n=(4*j+g) expects column c=(g<<7)|j
        const int dst = 4 * (c2 & 127) + (c2 >> 7);
        #pragma unroll
        for (int r = 0; r < ROWS; ++r)
            zx[(size_t)(t0 + r) * G4 + dst] = __float2half(acc[r]);
    }
}

// ---------------------------------------------------------------- scan kernel
__global__ __launch_bounds__(512, 2) void scan_kernel(
    const __half* __restrict__ zx, const float* __restrict__ Wh,
    const int* __restrict__ mask, const float* __restrict__ W_lat,
    const float* __restrict__ b_lat, float* __restrict__ out)
{
    const int n = threadIdx.x;
    const int g = n & 3;          // gate index (i,f,g,o)
    const int j = n >> 2;         // hidden unit
    const int c = (g << 7) | j;   // column in the 4H weight matrices

    // Wh column in registers: 128 VGPRs (launch_bounds caps at 256)
    float w[HH];
    #pragma unroll
    for (int k = 0; k < HH; ++k) w[k] = Wh[k * G4 + c];

    __shared__ float hbuf[2][HH];
    if (n < HH) { hbuf[0][n] = 0.f; hbuf[1][n] = 0.f; }
    float c_st = 0.f, h_st = 0.f;
    __syncthreads();

    int p = 0;
    float zcur = __half2float(zx[n]);
    int   mcur = mask[0];
    for (int t = 0; t < TT; ++t) {
        // prefetch next step's zx/mask (1 step of latency cover)
        const int tn = (t + 1 < TT) ? (t + 1) : t;
        const __half znext = zx[(size_t)tn * G4 + n];
        const int   mnext = mask[tn];

        // z_c = zx[t][c] + h . Wh[:,c]   (LDS broadcast reads, float4)
        float acc = zcur;
        const float4* hv = (const float4*)hbuf[p];
        #pragma unroll
        for (int k4 = 0; k4 < HH / 4; ++k4) {
            float4 h4 = hv[k4];
            acc += h4.x * w[4*k4+0] + h4.y * w[4*k4+1]
                 + h4.z * w[4*k4+2] + h4.w * w[4*k4+3];
        }

        // quad exchange: lanes 4j..4j+3 hold z for gates g=0..3 of unit j
        const float v1 = __shfl_xor(acc, 1);
        const float v2 = __shfl_xor(acc, 2);
        const float v3 = __shfl_xor(acc, 3);
        // gate m's value came from xor-distance d = g ^ m
        const float zi = (g==0)?acc : (g==1)?v1  : (g==2)?v2  : v3;
        const float zf = (g==0)?v1  : (g==1)?acc : (g==2)?v3  : v2;
        const float zg = (g==0)?v2  : (g==1)?v3  : (g==2)?acc : v1;
        const float zo = (g==0)?v3  : (g==1)?v2  : (g==2)?v1  : acc;

        const float i_s = 1.f / (1.f + __expf(-zi));
        const float f_s = 1.f / (1.f + __expf(-zf));
        const float o_s = 1.f / (1.f + __expf(-zo));
        const float g_t = 1.f - 2.f / (__expf(2.f * zg) + 1.f);   // tanh
        const float c_new = f_s * c_st + i_s * g_t;
        const float t_c   = 1.f - 2.f / (__expf(2.f * c_new) + 1.f);
        const float h_new = o_s * t_c;

        if (mcur) { c_st = c_new; h_st = h_new; }   // masked carry update
        if (g == 0) hbuf[p ^ 1][j] = h_st;          // publish h(t+1)
        __syncthreads();                            // single barrier per step
        p ^= 1;
        zcur = __half2float(znext);
        mcur = mnext;
    }

    // latent = h_f @ W_lat + b_lat  (16 outputs)
    if (n < 16) {
        float acc = b_lat[n];
        #pragma unroll
        for (int k = 0; k < HH; ++k) acc += hbuf[p][k] * W_lat[k * 16 + n];
        out[n] = acc;
    }
}

// ---------------------------------------------------------------- launcher
extern "C" void kernel_launch(void* const* d_in, const int* in_sizes, int n_in,
                              void* d_out, int out_size, void* d_ws, size_t ws_size,
                              hipStream_t stream) {
    const float* x      = (const float*)d_in[0];
    const int*   mask   = (const int*)  d_in[1];
    const float* W_in   = (const float*)d_in[2];
    const float* b_in   = (const float*)d_in[3];
    const float* Wi     = (const float*)d_in[4];
    const float* Wh     = (const float*)d_in[5];
    const float* b_lstm = (const float*)d_in[6];
    const float* W_lat  = (const float*)d_in[7];
    const float* b_lat  = (const float*)d_in[8];
    float* out = (float*)d_out;
    __half* zx = (__half*)d_ws;   // TT*512*2 = 64 MiB

    zx_kernel<<<TT / ROWS, 512, 0, stream>>>(x, W_in, b_in, Wi, b_lstm, zx);
    scan_kernel<<<1, 512, 0, stream>>>(zx, Wh, mask, W_lat, b_lat, out);
}

// Round 2
// 62433.051 us; speedup vs baseline: 1.2365x; 1.2365x over previous
//
#include <hip/hip_runtime.h>
#include <hip/hip_fp16.h>

// LSTMTrajectoryEncoder on MI355X.
// Phase 1 (parallel): zx[t][c] = b_lstm[c] + leaky_relu(x[t]@W_in + b_in) @ Wi[:,c]
//   stored f16 in ws, permuted to [t][4*unit+gate] for the scan.
// Phase 2 (serial, 1 block): thread n = (unit j=n>>2, k-quarter r=n&3).
//   Each thread holds Wh slice for ALL 4 gates of unit j over k in [32r,32r+32)
//   as 32 NAMED float4 registers (no array -> no scratch spill).
//   Butterfly shfl_xor(1,2) both reduces the split-K partials and broadcasts
//   all 4 gate values to every lane of the quad. One barrier per step.

#define TT   65536
#define DINN 128
#define HH   128
#define G4   512     // 4*H
#define NEG  0.01f
#define ROWS 16      // t-rows per GEMM block
#define QSTRIDE 40   // padded floats per h-quarter (4*40=160; quarters hit
                     // distinct bank groups: 40%32 = {0,8,16,24})

// ---------------------------------------------------------------- GEMM kernel
__global__ __launch_bounds__(512) void zx_kernel(
    const float* __restrict__ x, const float* __restrict__ W_in,
    const float* __restrict__ b_in, const float* __restrict__ Wi,
    const float* __restrict__ b_lstm, __half* __restrict__ zx)
{
    __shared__ float xt[ROWS][DINN];
    __shared__ float xp[ROWS][DINN];
    const int tid = threadIdx.x;
    const int t0  = blockIdx.x * ROWS;

    {
        const float4* src = (const float4*)(x + (size_t)t0 * DINN);
        ((float4*)&xt[0][0])[tid] = src[tid];
    }
    __syncthreads();

    {
        const int c  = tid & 127;
        const int r0 = tid >> 7;
        float a0 = b_in[c], a1 = a0, a2 = a0, a3 = a0;
        #pragma unroll
        for (int k4 = 0; k4 < DINN / 4; ++k4) {
            const float w0 = W_in[(k4*4+0)*DINN + c];
            const float w1 = W_in[(k4*4+1)*DINN + c];
            const float w2 = W_in[(k4*4+2)*DINN + c];
            const float w3 = W_in[(k4*4+3)*DINN + c];
            float4 v0 = *(const float4*)&xt[r0 +  0][k4*4];
            float4 v1 = *(const float4*)&xt[r0 +  4][k4*4];
            float4 v2 = *(const float4*)&xt[r0 +  8][k4*4];
            float4 v3 = *(const float4*)&xt[r0 + 12][k4*4];
            a0 += v0.x*w0 + v0.y*w1 + v0.z*w2 + v0.w*w3;
            a1 += v1.x*w0 + v1.y*w1 + v1.z*w2 + v1.w*w3;
            a2 += v2.x*w0 + v2.y*w1 + v2.z*w2 + v2.w*w3;
            a3 += v3.x*w0 + v3.y*w1 + v3.z*w2 + v3.w*w3;
        }
        xp[r0 +  0][c] = a0 >= 0.f ? a0 : NEG * a0;
        xp[r0 +  4][c] = a1 >= 0.f ? a1 : NEG * a1;
        xp[r0 +  8][c] = a2 >= 0.f ? a2 : NEG * a2;
        xp[r0 + 12][c] = a3 >= 0.f ? a3 : NEG * a3;
    }
    __syncthreads();

    {
        const int c2 = tid;
        float acc[ROWS];
        const float bl = b_lstm[c2];
        #pragma unroll
        for (int r = 0; r < ROWS; ++r) acc[r] = bl;
        #pragma unroll 4
        for (int k4 = 0; k4 < DINN / 4; ++k4) {
            const float w0 = Wi[(k4*4+0)*G4 + c2];
            const float w1 = Wi[(k4*4+1)*G4 + c2];
            const float w2 = Wi[(k4*4+2)*G4 + c2];
            const float w3 = Wi[(k4*4+3)*G4 + c2];
            #pragma unroll
            for (int r = 0; r < ROWS; ++r) {
                float4 a = *(const float4*)&xp[r][k4*4];
                acc[r] += a.x*w0 + a.y*w1 + a.z*w2 + a.w*w3;
            }
        }
        // dest layout [t][4*unit + gate]; c2 = gate*128 + unit
        const int dst = 4 * (c2 & 127) + (c2 >> 7);
        #pragma unroll
        for (int r = 0; r < ROWS; ++r)
            zx[(size_t)(t0 + r) * G4 + dst] = __float2half(acc[r]);
    }
}

// ---------------------------------------------------------------- scan kernel
// weight registers: w<g><q> = Wh[32r + 4q .. +3][(g<<7)|j] as float4
#define DECLW(g) float4 w##g##0, w##g##1, w##g##2, w##g##3, \
                        w##g##4, w##g##5, w##g##6, w##g##7;
#define LOADW(g,q) { const int kb = r*32 + q*4; const int cg = (g<<7)|j;   \
    w##g##q.x = Wh[(kb+0)*G4 + cg];  w##g##q.y = Wh[(kb+1)*G4 + cg];       \
    w##g##q.z = Wh[(kb+2)*G4 + cg];  w##g##q.w = Wh[(kb+3)*G4 + cg]; }
#define KGRP(q) { const float4 h4 = hq[q];                                  \
    p0 += h4.x*w0##q.x + h4.y*w0##q.y + h4.z*w0##q.z + h4.w*w0##q.w;        \
    p1 += h4.x*w1##q.x + h4.y*w1##q.y + h4.z*w1##q.z + h4.w*w1##q.w;        \
    p2 += h4.x*w2##q.x + h4.y*w2##q.y + h4.z*w2##q.z + h4.w*w2##q.w;        \
    p3 += h4.x*w3##q.x + h4.y*w3##q.y + h4.z*w3##q.z + h4.w*w3##q.w; }

__global__ __launch_bounds__(512, 2) void scan_kernel(
    const __half* __restrict__ zx, const float* __restrict__ Wh,
    const int* __restrict__ mask, const float* __restrict__ W_lat,
    const float* __restrict__ b_lat, float* __restrict__ out)
{
    const int n = threadIdx.x;
    const int j = n >> 2;        // hidden unit
    const int r = n & 3;         // k-quarter

    DECLW(0) DECLW(1) DECLW(2) DECLW(3)
    LOADW(0,0) LOADW(0,1) LOADW(0,2) LOADW(0,3)
    LOADW(0,4) LOADW(0,5) LOADW(0,6) LOADW(0,7)
    LOADW(1,0) LOADW(1,1) LOADW(1,2) LOADW(1,3)
    LOADW(1,4) LOADW(1,5) LOADW(1,6) LOADW(1,7)
    LOADW(2,0) LOADW(2,1) LOADW(2,2) LOADW(2,3)
    LOADW(2,4) LOADW(2,5) LOADW(2,6) LOADW(2,7)
    LOADW(3,0) LOADW(3,1) LOADW(3,2) LOADW(3,3)
    LOADW(3,4) LOADW(3,5) LOADW(3,6) LOADW(3,7)

    // h double buffer in padded-quarter layout: h[k] at (k>>5)*QSTRIDE + (k&31)
    __shared__ float hbuf[2][4 * QSTRIDE];
    if (n < 4 * QSTRIDE) { hbuf[0][n] = 0.f; hbuf[1][n] = 0.f; }
    float c_st = 0.f, h_st = 0.f;
    __syncthreads();

    const uint2* zx2 = (const uint2*)zx;   // 4 f16 gates per (t, unit)
    int p = 0;
    uint2 zcur = zx2[j];
    int   mcur = mask[0];

    for (int t = 0; t < TT; ++t) {
        const int tn = (t + 1 < TT) ? (t + 1) : t;
        const uint2 znext = zx2[(size_t)tn * HH + j];
        const int   mnext = mask[tn];

        // partial dots for 4 gates over this thread's k-quarter
        float p0 = 0.f, p1 = 0.f, p2 = 0.f, p3 = 0.f;
        const float4* hq = (const float4*)&hbuf[p][r * QSTRIDE];
        KGRP(0) KGRP(1) KGRP(2) KGRP(3) KGRP(4) KGRP(5) KGRP(6) KGRP(7)

        // butterfly: reduce quarters AND broadcast all gates to all quad lanes
        p0 += __shfl_xor(p0, 1); p1 += __shfl_xor(p1, 1);
        p2 += __shfl_xor(p2, 1); p3 += __shfl_xor(p3, 1);
        p0 += __shfl_xor(p0, 2); p1 += __shfl_xor(p1, 2);
        p2 += __shfl_xor(p2, 2); p3 += __shfl_xor(p3, 2);

        // add input contribution (4 f16: gates i,f,g,o of unit j)
        const __half2 zlo = *(const __half2*)&zcur.x;
        const __half2 zhi = *(const __half2*)&zcur.y;
        const float zi = p0 + __half2float(zlo.x);
        const float zf = p1 + __half2float(zlo.y);
        const float zg = p2 + __half2float(zhi.x);
        const float zo = p3 + __half2float(zhi.y);

        const float i_s = 1.f / (1.f + __expf(-zi));
        const float f_s = 1.f / (1.f + __expf(-zf));
        const float o_s = 1.f / (1.f + __expf(-zo));
        const float g_t = 1.f - 2.f / (__expf(2.f * zg) + 1.f);   // tanh
        const float c_new = f_s * c_st + i_s * g_t;
        const float t_c   = 1.f - 2.f / (__expf(2.f * c_new) + 1.f);
        const float h_new = o_s * t_c;

        if (mcur) { c_st = c_new; h_st = h_new; }
        if (r == 0) hbuf[p ^ 1][(j >> 5) * QSTRIDE + (j & 31)] = h_st;
        __syncthreads();
        p ^= 1;
        zcur = znext;
        mcur = mnext;
    }

    // latent = h_f @ W_lat + b_lat
    if (n < 16) {
        float acc = b_lat[n];
        #pragma unroll
        for (int k = 0; k < HH; ++k)
            acc += hbuf[p][(k >> 5) * QSTRIDE + (k & 31)] * W_lat[k * 16 + n];
        out[n] = acc;
    }
}

// ---------------------------------------------------------------- launcher
extern "C" void kernel_launch(void* const* d_in, const int* in_sizes, int n_in,
                              void* d_out, int out_size, void* d_ws, size_t ws_size,
                              hipStream_t stream) {
    const float* x      = (const float*)d_in[0];
    const int*   mask   = (const int*)  d_in[1];
    const float* W_in   = (const float*)d_in[2];
    const float* b_in   = (const float*)d_in[3];
    const float* Wi     = (const float*)d_in[4];
    const float* Wh     = (const float*)d_in[5];
    const float* b_lstm = (const float*)d_in[6];
    const float* W_lat  = (const float*)d_in[7];
    const float* b_lat  = (const float*)d_in[8];
    float* out = (float*)d_out;
    __half* zx = (__half*)d_ws;   // TT*512*2 = 64 MiB

    zx_kernel<<<TT / ROWS, 512, 0, stream>>>(x, W_in, b_in, Wi, b_lstm, zx);
    scan_kernel<<<1, 512, 0, stream>>>(zx, Wh, mask, W_lat, b_lat, out);
}

// Round 3
// 61274.780 us; speedup vs baseline: 1.2599x; 1.0189x over previous
//
#include <hip/hip_runtime.h>
#include <hip/hip_fp16.h>

// LSTMTrajectoryEncoder on MI355X.
// Phase 1 (parallel): zx[t][c] = b_lstm[c] + leaky_relu(x[t]@W_in + b_in) @ Wi[:,c]
//   stored f16 in ws, permuted to [t][4*unit+gate] for the scan.
// Phase 2 (serial, 1 block): thread n = (unit j=n>>2, k-quarter r=n&3).
//   Wh slice (4 gates x 32 k) held in 128 NAMED SCALAR floats, passed through
//   an empty asm block so LLVM cannot rematerialize the loads inside the loop
//   (round-2 failure mode: VGPR=88, 512 KB/step HBM re-fetch of Wh).
//   Butterfly shfl_xor(1,2) reduces split-K partials and broadcasts all 4
//   gate values to every quad lane. One barrier per step.

#define TT   65536
#define DINN 128
#define HH   128
#define G4   512     // 4*H
#define NEG  0.01f
#define ROWS 16      // t-rows per GEMM block
#define QSTRIDE 40   // padded floats per h-quarter: quarters start at banks {0,8,16,24}

// ---------------------------------------------------------------- GEMM kernel
__global__ __launch_bounds__(512) void zx_kernel(
    const float* __restrict__ x, const float* __restrict__ W_in,
    const float* __restrict__ b_in, const float* __restrict__ Wi,
    const float* __restrict__ b_lstm, __half* __restrict__ zx)
{
    __shared__ float xt[ROWS][DINN];
    __shared__ float xp[ROWS][DINN];
    const int tid = threadIdx.x;
    const int t0  = blockIdx.x * ROWS;

    {
        const float4* src = (const float4*)(x + (size_t)t0 * DINN);
        ((float4*)&xt[0][0])[tid] = src[tid];
    }
    __syncthreads();

    {
        const int c  = tid & 127;
        const int r0 = tid >> 7;
        float a0 = b_in[c], a1 = a0, a2 = a0, a3 = a0;
        #pragma unroll
        for (int k4 = 0; k4 < DINN / 4; ++k4) {
            const float w0 = W_in[(k4*4+0)*DINN + c];
            const float w1 = W_in[(k4*4+1)*DINN + c];
            const float w2 = W_in[(k4*4+2)*DINN + c];
            const float w3 = W_in[(k4*4+3)*DINN + c];
            float4 v0 = *(const float4*)&xt[r0 +  0][k4*4];
            float4 v1 = *(const float4*)&xt[r0 +  4][k4*4];
            float4 v2 = *(const float4*)&xt[r0 +  8][k4*4];
            float4 v3 = *(const float4*)&xt[r0 + 12][k4*4];
            a0 += v0.x*w0 + v0.y*w1 + v0.z*w2 + v0.w*w3;
            a1 += v1.x*w0 + v1.y*w1 + v1.z*w2 + v1.w*w3;
            a2 += v2.x*w0 + v2.y*w1 + v2.z*w2 + v2.w*w3;
            a3 += v3.x*w0 + v3.y*w1 + v3.z*w2 + v3.w*w3;
        }
        xp[r0 +  0][c] = a0 >= 0.f ? a0 : NEG * a0;
        xp[r0 +  4][c] = a1 >= 0.f ? a1 : NEG * a1;
        xp[r0 +  8][c] = a2 >= 0.f ? a2 : NEG * a2;
        xp[r0 + 12][c] = a3 >= 0.f ? a3 : NEG * a3;
    }
    __syncthreads();

    {
        const int c2 = tid;
        float acc[ROWS];
        const float bl = b_lstm[c2];
        #pragma unroll
        for (int r = 0; r < ROWS; ++r) acc[r] = bl;
        #pragma unroll 4
        for (int k4 = 0; k4 < DINN / 4; ++k4) {
            const float w0 = Wi[(k4*4+0)*G4 + c2];
            const float w1 = Wi[(k4*4+1)*G4 + c2];
            const float w2 = Wi[(k4*4+2)*G4 + c2];
            const float w3 = Wi[(k4*4+3)*G4 + c2];
            #pragma unroll
            for (int r = 0; r < ROWS; ++r) {
                float4 a = *(const float4*)&xp[r][k4*4];
                acc[r] += a.x*w0 + a.y*w1 + a.z*w2 + a.w*w3;
            }
        }
        // dest layout [t][4*unit + gate]; c2 = gate*128 + unit
        const int dst = 4 * (c2 & 127) + (c2 >> 7);
        #pragma unroll
        for (int r = 0; r < ROWS; ++r)
            zx[(size_t)(t0 + r) * G4 + dst] = __float2half(acc[r]);
    }
}

// ---------------------------------------------------------------- scan kernel
// 128 scalar weight registers: w<g><q>{x,y,z,w} = Wh[32r+4q+e][(g<<7)|j]
#define DW(g,q)  float w##g##q##x, w##g##q##y, w##g##q##z, w##g##q##w;
#define LW(g,q)  { const int kb = (r<<5) + (q<<2); const int cg = (g<<7)|j; \
    w##g##q##x = Wh[(kb+0)*G4 + cg];  w##g##q##y = Wh[(kb+1)*G4 + cg];      \
    w##g##q##z = Wh[(kb+2)*G4 + cg];  w##g##q##w = Wh[(kb+3)*G4 + cg]; }
#define PINQ(g,q) asm volatile("" : "+v"(w##g##q##x), "+v"(w##g##q##y), \
                                    "+v"(w##g##q##z), "+v"(w##g##q##w));
#define KG(g,q)  (h4.x*w##g##q##x + h4.y*w##g##q##y + h4.z*w##g##q##z + h4.w*w##g##q##w)
#define KGRP(q)  { const float4 h4 = hq[q];  \
    p0 += KG(0,q); p1 += KG(1,q); p2 += KG(2,q); p3 += KG(3,q); }

#define ALLG(M,q) M(0,q) M(1,q) M(2,q) M(3,q)
#define ALLQ(M)   ALLG(M,0) ALLG(M,1) ALLG(M,2) ALLG(M,3) \
                  ALLG(M,4) ALLG(M,5) ALLG(M,6) ALLG(M,7)

__global__ __launch_bounds__(512, 2) void scan_kernel(
    const __half* __restrict__ zx, const float* __restrict__ Wh,
    const int* __restrict__ mask, const float* __restrict__ W_lat,
    const float* __restrict__ b_lat, float* __restrict__ out)
{
    const int n = threadIdx.x;
    const int j = n >> 2;        // hidden unit
    const int r = n & 3;         // k-quarter

    ALLQ(DW)          // declare 128 scalars
    ALLQ(LW)          // load them
    ALLQ(PINQ)        // opaque asm: kill rematerialization

    // h double buffer, padded-quarter layout: h[k] at (k>>5)*QSTRIDE + (k&31)
    __shared__ float hbuf[2][4 * QSTRIDE];
    if (n < 4 * QSTRIDE) { hbuf[0][n] = 0.f; hbuf[1][n] = 0.f; }
    float c_st = 0.f, h_st = 0.f;
    __syncthreads();

    const uint2* zx2 = (const uint2*)zx;   // 4 f16 gates per (t, unit)
    int p = 0;
    uint2 zcur = zx2[j];
    int   mcur = mask[0];

    for (int t = 0; t < TT; ++t) {
        const int tn = (t + 1 < TT) ? (t + 1) : t;
        const uint2 znext = zx2[(size_t)tn * HH + j];
        const int   mnext = mask[tn];

        // partial dots for 4 gates over this thread's k-quarter
        float p0 = 0.f, p1 = 0.f, p2 = 0.f, p3 = 0.f;
        const float4* hq = (const float4*)&hbuf[p][r * QSTRIDE];
        KGRP(0) KGRP(1) KGRP(2) KGRP(3) KGRP(4) KGRP(5) KGRP(6) KGRP(7)

        // butterfly: reduce quarters AND broadcast gates to all quad lanes
        p0 += __shfl_xor(p0, 1); p1 += __shfl_xor(p1, 1);
        p2 += __shfl_xor(p2, 1); p3 += __shfl_xor(p3, 1);
        p0 += __shfl_xor(p0, 2); p1 += __shfl_xor(p1, 2);
        p2 += __shfl_xor(p2, 2); p3 += __shfl_xor(p3, 2);

        // add input contribution (4 f16: gates i,f,g,o of unit j)
        const __half2 zlo = *(const __half2*)&zcur.x;
        const __half2 zhi = *(const __half2*)&zcur.y;
        const float zi = p0 + __half2float(zlo.x);
        const float zf = p1 + __half2float(zlo.y);
        const float zg = p2 + __half2float(zhi.x);
        const float zo = p3 + __half2float(zhi.y);

        const float i_s = 1.f / (1.f + __expf(-zi));
        const float f_s = 1.f / (1.f + __expf(-zf));
        const float o_s = 1.f / (1.f + __expf(-zo));
        const float g_t = 1.f - 2.f / (__expf(2.f * zg) + 1.f);   // tanh
        const float c_new = f_s * c_st + i_s * g_t;
        const float t_c   = 1.f - 2.f / (__expf(2.f * c_new) + 1.f);
        const float h_new = o_s * t_c;

        if (mcur) { c_st = c_new; h_st = h_new; }
        if (r == 0) hbuf[p ^ 1][(j >> 5) * QSTRIDE + (j & 31)] = h_st;
        __syncthreads();
        p ^= 1;
        zcur = znext;
        mcur = mnext;
    }

    // latent = h_f @ W_lat + b_lat
    if (n < 16) {
        float acc = b_lat[n];
        #pragma unroll
        for (int k = 0; k < HH; ++k)
            acc += hbuf[p][(k >> 5) * QSTRIDE + (k & 31)] * W_lat[k * 16 + n];
        out[n] = acc;
    }
}

// ---------------------------------------------------------------- launcher
extern "C" void kernel_launch(void* const* d_in, const int* in_sizes, int n_in,
                              void* d_out, int out_size, void* d_ws, size_t ws_size,
                              hipStream_t stream) {
    const float* x      = (const float*)d_in[0];
    const int*   mask   = (const int*)  d_in[1];
    const float* W_in   = (const float*)d_in[2];
    const float* b_in   = (const float*)d_in[3];
    const float* Wi     = (const float*)d_in[4];
    const float* Wh     = (const float*)d_in[5];
    const float* b_lstm = (const float*)d_in[6];
    const float* W_lat  = (const float*)d_in[7];
    const float* b_lat  = (const float*)d_in[8];
    float* out = (float*)d_out;
    __half* zx = (__half*)d_ws;   // TT*512*2 = 64 MiB

    zx_kernel<<<TT / ROWS, 512, 0, stream>>>(x, W_in, b_in, Wi, b_lstm, zx);
    scan_kernel<<<1, 512, 0, stream>>>(zx, Wh, mask, W_lat, b_lat, out);
}

// Round 4
// 47353.732 us; speedup vs baseline: 1.6302x; 1.2940x over previous
//
#include <hip/hip_runtime.h>
#include <hip/hip_fp16.h>

// LSTMTrajectoryEncoder on MI355X.
// Phase 1 (parallel): zx[t][c] = b_lstm[c] + leaky_relu(x[t]@W_in + b_in) @ Wi[:,c]
//   stored f16 in ws, permuted to [t][4*unit+gate] for the scan.
// Phase 2 (serial, 1 block): thread n = (unit j=n>>2, k-quarter r=n&3).
//   Wh slice (4 gates x 32 k) held as 64 packed-f16 half2 VGPRs (fits under the
//   128-VGPR pressure cliff that defeated rounds 1-3), consumed by
//   v_dot2_f32_f16 with fp32 accumulate. h lives in LDS as f16.
//   Butterfly shfl_xor(1,2) reduces split-K partials and broadcasts all 4
//   gate values to every quad lane. One barrier per step.

#define TT   65536
#define DINN 128
#define HH   128
#define G4   512     // 4*H
#define NEG  0.01f
#define ROWS 16      // t-rows per GEMM block

typedef _Float16 half2_t __attribute__((ext_vector_type(2)));

#if defined(__has_builtin)
#if __has_builtin(__builtin_amdgcn_fdot2)
#define FDOT2(a, b, c) __builtin_amdgcn_fdot2((a), (b), (c), false)
#endif
#endif
#ifndef FDOT2
__device__ __forceinline__ float fdot2_sw(half2_t a, half2_t b, float c) {
    return c + (float)a[0] * (float)b[0] + (float)a[1] * (float)b[1];
}
#define FDOT2(a, b, c) fdot2_sw((a), (b), (c))
#endif

// ---------------------------------------------------------------- GEMM kernel
__global__ __launch_bounds__(512) void zx_kernel(
    const float* __restrict__ x, const float* __restrict__ W_in,
    const float* __restrict__ b_in, const float* __restrict__ Wi,
    const float* __restrict__ b_lstm, __half* __restrict__ zx)
{
    __shared__ float xt[ROWS][DINN];
    __shared__ float xp[ROWS][DINN];
    const int tid = threadIdx.x;
    const int t0  = blockIdx.x * ROWS;

    {
        const float4* src = (const float4*)(x + (size_t)t0 * DINN);
        ((float4*)&xt[0][0])[tid] = src[tid];
    }
    __syncthreads();

    {
        const int c  = tid & 127;
        const int r0 = tid >> 7;
        float a0 = b_in[c], a1 = a0, a2 = a0, a3 = a0;
        #pragma unroll
        for (int k4 = 0; k4 < DINN / 4; ++k4) {
            const float w0 = W_in[(k4*4+0)*DINN + c];
            const float w1 = W_in[(k4*4+1)*DINN + c];
            const float w2 = W_in[(k4*4+2)*DINN + c];
            const float w3 = W_in[(k4*4+3)*DINN + c];
            float4 v0 = *(const float4*)&xt[r0 +  0][k4*4];
            float4 v1 = *(const float4*)&xt[r0 +  4][k4*4];
            float4 v2 = *(const float4*)&xt[r0 +  8][k4*4];
            float4 v3 = *(const float4*)&xt[r0 + 12][k4*4];
            a0 += v0.x*w0 + v0.y*w1 + v0.z*w2 + v0.w*w3;
            a1 += v1.x*w0 + v1.y*w1 + v1.z*w2 + v1.w*w3;
            a2 += v2.x*w0 + v2.y*w1 + v2.z*w2 + v2.w*w3;
            a3 += v3.x*w0 + v3.y*w1 + v3.z*w2 + v3.w*w3;
        }
        xp[r0 +  0][c] = a0 >= 0.f ? a0 : NEG * a0;
        xp[r0 +  4][c] = a1 >= 0.f ? a1 : NEG * a1;
        xp[r0 +  8][c] = a2 >= 0.f ? a2 : NEG * a2;
        xp[r0 + 12][c] = a3 >= 0.f ? a3 : NEG * a3;
    }
    __syncthreads();

    {
        const int c2 = tid;
        float acc[ROWS];
        const float bl = b_lstm[c2];
        #pragma unroll
        for (int r = 0; r < ROWS; ++r) acc[r] = bl;
        #pragma unroll 4
        for (int k4 = 0; k4 < DINN / 4; ++k4) {
            const float w0 = Wi[(k4*4+0)*G4 + c2];
            const float w1 = Wi[(k4*4+1)*G4 + c2];
            const float w2 = Wi[(k4*4+2)*G4 + c2];
            const float w3 = Wi[(k4*4+3)*G4 + c2];
            #pragma unroll
            for (int r = 0; r < ROWS; ++r) {
                float4 a = *(const float4*)&xp[r][k4*4];
                acc[r] += a.x*w0 + a.y*w1 + a.z*w2 + a.w*w3;
            }
        }
        // dest layout [t][4*unit + gate]; c2 = gate*128 + unit
        const int dst = 4 * (c2 & 127) + (c2 >> 7);
        #pragma unroll
        for (int r = 0; r < ROWS; ++r)
            zx[(size_t)(t0 + r) * G4 + dst] = __float2half(acc[r]);
    }
}

// ---------------------------------------------------------------- scan kernel
// 64 packed weight regs: w<g>_<p> = half2( Wh[kb][cg], Wh[kb+1][cg] ),
// kb = 32r + 2p, cg = (g<<7)|j, stored as unsigned (bit-cast at use).
#define DW(g,p)  unsigned w##g##_##p;
#define LW(g,p)  { const int kb = (r<<5) + 2*(p); const int cg = ((g)<<7)|j; \
    half2_t v_; v_[0] = (_Float16)Wh[(kb+0)*G4 + cg];                        \
    v_[1] = (_Float16)Wh[(kb+1)*G4 + cg];                                    \
    w##g##_##p = __builtin_bit_cast(unsigned, v_); }
#define PIN(g,p) asm volatile("" : "+v"(w##g##_##p));

#define BCH(u) __builtin_bit_cast(half2_t, (u))
#define DOTP(p, hu) {                          \
    const half2_t h_ = BCH(hu);                \
    p0 = FDOT2(h_, BCH(w0##_##p), p0);         \
    p1 = FDOT2(h_, BCH(w1##_##p), p1);         \
    p2 = FDOT2(h_, BCH(w2##_##p), p2);         \
    p3 = FDOT2(h_, BCH(w3##_##p), p3); }

#define FORP(M,g) M(g,0) M(g,1) M(g,2) M(g,3) M(g,4) M(g,5) M(g,6) M(g,7) \
                  M(g,8) M(g,9) M(g,10) M(g,11) M(g,12) M(g,13) M(g,14) M(g,15)
#define FORALL(M) FORP(M,0) FORP(M,1) FORP(M,2) FORP(M,3)

__global__ __launch_bounds__(512)
__attribute__((amdgpu_waves_per_eu(2, 2)))
void scan_kernel(
    const __half* __restrict__ zx, const float* __restrict__ Wh,
    const int* __restrict__ mask, const float* __restrict__ W_lat,
    const float* __restrict__ b_lat, float* __restrict__ out)
{
    const int n = threadIdx.x;
    const int j = n >> 2;        // hidden unit
    const int r = n & 3;         // k-quarter

    FORALL(DW)       // declare 64 packed half2 regs
    FORALL(LW)       // load + convert f32 -> f16
    FORALL(PIN)      // opaque asm: kill rematerialization

    // h double buffer (f16) + fp32 final-h buffer for the latent projection
    __shared__ __half hbuf[2][HH];
    __shared__ float  hfin[HH];
    if (n < HH) { hbuf[0][n] = __float2half(0.f); hbuf[1][n] = __float2half(0.f); }
    float c_st = 0.f, h_st = 0.f;
    __syncthreads();

    const uint2* zx2 = (const uint2*)zx;   // 4 f16 gates per (t, unit)
    int p = 0;
    uint2 zcur = zx2[j];
    int   mcur = mask[0];

    for (int t = 0; t < TT; ++t) {
        const int tn = (t + 1 < TT) ? (t + 1) : t;
        const uint2 znext = zx2[(size_t)tn * HH + j];
        const int   mnext = mask[tn];

        // partial dots for 4 gates over this thread's 32-element h-quarter
        float p0 = 0.f, p1 = 0.f, p2 = 0.f, p3 = 0.f;
        const uint4* hp4 = (const uint4*)&hbuf[p][r << 5];   // 64 B, 16B-aligned
        const uint4 ha = hp4[0], hb = hp4[1], hc = hp4[2], hd = hp4[3];
        DOTP(0,  ha.x) DOTP(1,  ha.y) DOTP(2,  ha.z) DOTP(3,  ha.w)
        DOTP(4,  hb.x) DOTP(5,  hb.y) DOTP(6,  hb.z) DOTP(7,  hb.w)
        DOTP(8,  hc.x) DOTP(9,  hc.y) DOTP(10, hc.z) DOTP(11, hc.w)
        DOTP(12, hd.x) DOTP(13, hd.y) DOTP(14, hd.z) DOTP(15, hd.w)

        // butterfly: reduce quarters AND broadcast gates to all quad lanes
        p0 += __shfl_xor(p0, 1); p1 += __shfl_xor(p1, 1);
        p2 += __shfl_xor(p2, 1); p3 += __shfl_xor(p3, 1);
        p0 += __shfl_xor(p0, 2); p1 += __shfl_xor(p1, 2);
        p2 += __shfl_xor(p2, 2); p3 += __shfl_xor(p3, 2);

        // add input contribution (4 f16: gates i,f,g,o of unit j)
        const __half2 zlo = *(const __half2*)&zcur.x;
        const __half2 zhi = *(const __half2*)&zcur.y;
        const float zi = p0 + __half2float(zlo.x);
        const float zf = p1 + __half2float(zlo.y);
        const float zg = p2 + __half2float(zhi.x);
        const float zo = p3 + __half2float(zhi.y);

        const float i_s = 1.f / (1.f + __expf(-zi));
        const float f_s = 1.f / (1.f + __expf(-zf));
        const float o_s = 1.f / (1.f + __expf(-zo));
        const float g_t = 1.f - 2.f / (__expf(2.f * zg) + 1.f);   // tanh
        const float c_new = f_s * c_st + i_s * g_t;
        const float t_c   = 1.f - 2.f / (__expf(2.f * c_new) + 1.f);
        const float h_new = o_s * t_c;

        if (mcur) { c_st = c_new; h_st = h_new; }
        if (r == 0) hbuf[p ^ 1][j] = __float2half(h_st);
        __syncthreads();
        p ^= 1;
        zcur = znext;
        mcur = mnext;
    }

    // latent = h_f @ W_lat + b_lat  (fp32 final h for precision)
    if (r == 0) hfin[j] = h_st;
    __syncthreads();
    if (n < 16) {
        float acc = b_lat[n];
        #pragma unroll
        for (int k = 0; k < HH; ++k) acc += hfin[k] * W_lat[k * 16 + n];
        out[n] = acc;
    }
}

// ---------------------------------------------------------------- launcher
extern "C" void kernel_launch(void* const* d_in, const int* in_sizes, int n_in,
                              void* d_out, int out_size, void* d_ws, size_t ws_size,
                              hipStream_t stream) {
    const float* x      = (const float*)d_in[0];
    const int*   mask   = (const int*)  d_in[1];
    const float* W_in   = (const float*)d_in[2];
    const float* b_in   = (const float*)d_in[3];
    const float* Wi     = (const float*)d_in[4];
    const float* Wh     = (const float*)d_in[5];
    const float* b_lstm = (const float*)d_in[6];
    const float* W_lat  = (const float*)d_in[7];
    const float* b_lat  = (const float*)d_in[8];
    float* out = (float*)d_out;
    __half* zx = (__half*)d_ws;   // TT*512*2 = 64 MiB

    zx_kernel<<<TT / ROWS, 512, 0, stream>>>(x, W_in, b_in, Wi, b_lstm, zx);
    scan_kernel<<<1, 512, 0, stream>>>(zx, Wh, mask, W_lat, b_lat, out);
}

// Round 5
// 36124.417 us; speedup vs baseline: 2.1370x; 1.3109x over previous
//
#include <hip/hip_runtime.h>
#include <hip/hip_fp16.h>

// LSTMTrajectoryEncoder on MI355X.
// Phase 1 (parallel): zx[t][c] = b_lstm[c] + leaky_relu(x[t]@W_in + b_in) @ Wi[:,c]
//   stored f16 in ws, permuted to [t][4*unit+gate].
// Phase 1b: mask compaction — masked steps are exact carry no-ops, so a
//   prefix-sum kernel emits idx[] of active steps (~90%) and the scan skips
//   the rest. All mask logic leaves the inner loop.
// Phase 2 (serial, 1 block, 256 thr = unit j x k-half s, 1 wave/SIMD):
//   Wh slice (4 gates x 64 k) = 128 packed-f16 half2 VGPRs (512-VGPR budget
//   at 1 wave/EU), v_dot2_f32_f16 fp32-accumulate, h in LDS as f16,
//   one shfl_xor round + one barrier per step, 2-deep idx/zx prefetch.

#define TT   65536
#define DINN 128
#define HH   128
#define G4   512     // 4*H
#define NEG  0.01f
#define ROWS 16      // t-rows per GEMM block
#define CTH  1024    // compaction threads

typedef _Float16 half2_t __attribute__((ext_vector_type(2)));

#if defined(__has_builtin)
#if __has_builtin(__builtin_amdgcn_fdot2)
#define FDOT2(a, b, c) __builtin_amdgcn_fdot2((a), (b), (c), false)
#endif
#endif
#ifndef FDOT2
__device__ __forceinline__ float fdot2_sw(half2_t a, half2_t b, float c) {
    return c + (float)a[0] * (float)b[0] + (float)a[1] * (float)b[1];
}
#define FDOT2(a, b, c) fdot2_sw((a), (b), (c))
#endif

// ---------------------------------------------------------------- GEMM kernel
__global__ __launch_bounds__(512) void zx_kernel(
    const float* __restrict__ x, const float* __restrict__ W_in,
    const float* __restrict__ b_in, const float* __restrict__ Wi,
    const float* __restrict__ b_lstm, __half* __restrict__ zx)
{
    __shared__ float xt[ROWS][DINN];
    __shared__ float xp[ROWS][DINN];
    const int tid = threadIdx.x;
    const int t0  = blockIdx.x * ROWS;

    {
        const float4* src = (const float4*)(x + (size_t)t0 * DINN);
        ((float4*)&xt[0][0])[tid] = src[tid];
    }
    __syncthreads();

    {
        const int c  = tid & 127;
        const int r0 = tid >> 7;
        float a0 = b_in[c], a1 = a0, a2 = a0, a3 = a0;
        #pragma unroll
        for (int k4 = 0; k4 < DINN / 4; ++k4) {
            const float w0 = W_in[(k4*4+0)*DINN + c];
            const float w1 = W_in[(k4*4+1)*DINN + c];
            const float w2 = W_in[(k4*4+2)*DINN + c];
            const float w3 = W_in[(k4*4+3)*DINN + c];
            float4 v0 = *(const float4*)&xt[r0 +  0][k4*4];
            float4 v1 = *(const float4*)&xt[r0 +  4][k4*4];
            float4 v2 = *(const float4*)&xt[r0 +  8][k4*4];
            float4 v3 = *(const float4*)&xt[r0 + 12][k4*4];
            a0 += v0.x*w0 + v0.y*w1 + v0.z*w2 + v0.w*w3;
            a1 += v1.x*w0 + v1.y*w1 + v1.z*w2 + v1.w*w3;
            a2 += v2.x*w0 + v2.y*w1 + v2.z*w2 + v2.w*w3;
            a3 += v3.x*w0 + v3.y*w1 + v3.z*w2 + v3.w*w3;
        }
        xp[r0 +  0][c] = a0 >= 0.f ? a0 : NEG * a0;
        xp[r0 +  4][c] = a1 >= 0.f ? a1 : NEG * a1;
        xp[r0 +  8][c] = a2 >= 0.f ? a2 : NEG * a2;
        xp[r0 + 12][c] = a3 >= 0.f ? a3 : NEG * a3;
    }
    __syncthreads();

    {
        const int c2 = tid;
        float acc[ROWS];
        const float bl = b_lstm[c2];
        #pragma unroll
        for (int r = 0; r < ROWS; ++r) acc[r] = bl;
        #pragma unroll 4
        for (int k4 = 0; k4 < DINN / 4; ++k4) {
            const float w0 = Wi[(k4*4+0)*G4 + c2];
            const float w1 = Wi[(k4*4+1)*G4 + c2];
            const float w2 = Wi[(k4*4+2)*G4 + c2];
            const float w3 = Wi[(k4*4+3)*G4 + c2];
            #pragma unroll
            for (int r = 0; r < ROWS; ++r) {
                float4 a = *(const float4*)&xp[r][k4*4];
                acc[r] += a.x*w0 + a.y*w1 + a.z*w2 + a.w*w3;
            }
        }
        // dest layout [t][4*unit + gate]; c2 = gate*128 + unit
        const int dst = 4 * (c2 & 127) + (c2 >> 7);
        #pragma unroll
        for (int r = 0; r < ROWS; ++r)
            zx[(size_t)(t0 + r) * G4 + dst] = __float2half(acc[r]);
    }
}

// ---------------------------------------------------------- compaction kernel
__global__ __launch_bounds__(CTH) void compact_kernel(
    const int* __restrict__ mask, int* __restrict__ idx, int* __restrict__ cnt_out)
{
    __shared__ int sc[CTH];
    const int th   = threadIdx.x;
    const int base = th * (TT / CTH);
    int cnt = 0;
    #pragma unroll 8
    for (int k = 0; k < TT / CTH; ++k) cnt += (mask[base + k] != 0);
    sc[th] = cnt;
    __syncthreads();
    for (int off = 1; off < CTH; off <<= 1) {      // inclusive Hillis-Steele
        int v = sc[th];
        int u = (th >= off) ? sc[th - off] : 0;
        __syncthreads();
        sc[th] = v + u;
        __syncthreads();
    }
    int pos = sc[th] - cnt;                        // exclusive prefix
    for (int k = 0; k < TT / CTH; ++k) {
        int t = base + k;
        if (mask[t]) idx[pos++] = t;
    }
    __syncthreads();                               // global writes visible in-block
    if (th == 0) {
        int total = sc[CTH - 1];
        int last  = (total > 0) ? idx[total - 1] : 0;
        idx[total]     = last;                     // pad for 2-deep prefetch
        idx[total + 1] = last;
        cnt_out[0] = total;
    }
}

// ---------------------------------------------------------------- scan kernel
// 128 packed weight regs: w<g>_<p> = half2( Wh[kb][cg], Wh[kb+1][cg] ),
// kb = 64s + 2p (p in [0,32)), cg = (g<<7)|j.
#define DW(g,p)  unsigned w##g##_##p;
#define LW(g,p)  { const int kb = (s<<6) + 2*(p); const int cg = ((g)<<7)|j; \
    half2_t v_; v_[0] = (_Float16)Wh[(kb+0)*G4 + cg];                        \
    v_[1] = (_Float16)Wh[(kb+1)*G4 + cg];                                    \
    w##g##_##p = __builtin_bit_cast(unsigned, v_); }
#define PIN(g,p) asm volatile("" : "+v"(w##g##_##p));

#define BCH(u) __builtin_bit_cast(half2_t, (u))
#define DOTP(p, hu) {                          \
    const half2_t h_ = BCH(hu);                \
    p0 = FDOT2(h_, BCH(w0##_##p), p0);         \
    p1 = FDOT2(h_, BCH(w1##_##p), p1);         \
    p2 = FDOT2(h_, BCH(w2##_##p), p2);         \
    p3 = FDOT2(h_, BCH(w3##_##p), p3); }

#define FORP(M,g) M(g,0)  M(g,1)  M(g,2)  M(g,3)  M(g,4)  M(g,5)  M(g,6)  M(g,7)  \
                  M(g,8)  M(g,9)  M(g,10) M(g,11) M(g,12) M(g,13) M(g,14) M(g,15) \
                  M(g,16) M(g,17) M(g,18) M(g,19) M(g,20) M(g,21) M(g,22) M(g,23) \
                  M(g,24) M(g,25) M(g,26) M(g,27) M(g,28) M(g,29) M(g,30) M(g,31)
#define FORALL(M) FORP(M,0) FORP(M,1) FORP(M,2) FORP(M,3)

__global__ __launch_bounds__(256, 1) void scan_kernel(
    const __half* __restrict__ zx, const float* __restrict__ Wh,
    const int* __restrict__ idx, const int* __restrict__ cnt,
    const float* __restrict__ W_lat, const float* __restrict__ b_lat,
    float* __restrict__ out)
{
    const int n = threadIdx.x;
    const int j = n >> 1;        // hidden unit
    const int s = n & 1;         // k-half

    FORALL(DW)       // 128 packed half2 regs
    FORALL(LW)       // load + convert f32 -> f16
    FORALL(PIN)      // opaque asm: kill rematerialization

    __shared__ __half hbuf[2][HH];
    __shared__ float  hfin[HH];
    ((__half*)hbuf)[n] = __float2half(0.f);   // n<256 covers both buffers
    float c_st = 0.f, h_st = 0.f;
    __syncthreads();

    const int S = cnt[0];
    const uint2* zx2 = (const uint2*)zx;   // 4 f16 gates per (t, unit)
    int p = 0;
    int  t1i  = idx[1];
    uint2 zcur = zx2[(size_t)idx[0] * HH + j];

    for (int i = 0; i < S; ++i) {
        const int  t2i   = idx[i + 2];                      // 2-deep prefetch
        const uint2 znext = zx2[(size_t)t1i * HH + j];

        // partial dots for 4 gates over this thread's 64-element h-half
        float p0 = 0.f, p1 = 0.f, p2 = 0.f, p3 = 0.f;
        const uint4* hp4 = (const uint4*)&hbuf[p][s << 6];  // 128 B
        const uint4 ha = hp4[0], hb = hp4[1], hc = hp4[2], hd = hp4[3];
        const uint4 he = hp4[4], hf = hp4[5], hg = hp4[6], hh = hp4[7];
        DOTP(0,  ha.x) DOTP(1,  ha.y) DOTP(2,  ha.z) DOTP(3,  ha.w)
        DOTP(4,  hb.x) DOTP(5,  hb.y) DOTP(6,  hb.z) DOTP(7,  hb.w)
        DOTP(8,  hc.x) DOTP(9,  hc.y) DOTP(10, hc.z) DOTP(11, hc.w)
        DOTP(12, hd.x) DOTP(13, hd.y) DOTP(14, hd.z) DOTP(15, hd.w)
        DOTP(16, he.x) DOTP(17, he.y) DOTP(18, he.z) DOTP(19, he.w)
        DOTP(20, hf.x) DOTP(21, hf.y) DOTP(22, hf.z) DOTP(23, hf.w)
        DOTP(24, hg.x) DOTP(25, hg.y) DOTP(26, hg.z) DOTP(27, hg.w)
        DOTP(28, hh.x) DOTP(29, hh.y) DOTP(30, hh.z) DOTP(31, hh.w)

        // single reduce round: lane pair (s=0,1) -> both get full gate sums
        p0 += __shfl_xor(p0, 1);
        p1 += __shfl_xor(p1, 1);
        p2 += __shfl_xor(p2, 1);
        p3 += __shfl_xor(p3, 1);

        // add input contribution (4 f16: gates i,f,g,o of unit j)
        const __half2 zlo = *(const __half2*)&zcur.x;
        const __half2 zhi = *(const __half2*)&zcur.y;
        const float zi = p0 + __half2float(zlo.x);
        const float zf = p1 + __half2float(zlo.y);
        const float zg = p2 + __half2float(zhi.x);
        const float zo = p3 + __half2float(zhi.y);

        const float i_s = 1.f / (1.f + __expf(-zi));
        const float f_s = 1.f / (1.f + __expf(-zf));
        const float o_s = 1.f / (1.f + __expf(-zo));
        const float g_t = 1.f - 2.f / (__expf(2.f * zg) + 1.f);   // tanh
        c_st = f_s * c_st + i_s * g_t;          // unconditional: steps compacted
        const float t_c = 1.f - 2.f / (__expf(2.f * c_st) + 1.f);
        h_st = o_s * t_c;

        if (s == 0) hbuf[p ^ 1][j] = __float2half(h_st);
        __syncthreads();
        p ^= 1;
        zcur = znext;
        t1i  = t2i;
    }

    // latent = h_f @ W_lat + b_lat  (fp32 final h for precision)
    if (s == 0) hfin[j] = h_st;
    __syncthreads();
    if (n < 16) {
        float acc = b_lat[n];
        #pragma unroll
        for (int k = 0; k < HH; ++k) acc += hfin[k] * W_lat[k * 16 + n];
        out[n] = acc;
    }
}

// ---------------------------------------------------------------- launcher
extern "C" void kernel_launch(void* const* d_in, const int* in_sizes, int n_in,
                              void* d_out, int out_size, void* d_ws, size_t ws_size,
                              hipStream_t stream) {
    const float* x      = (const float*)d_in[0];
    const int*   mask   = (const int*)  d_in[1];
    const float* W_in   = (const float*)d_in[2];
    const float* b_in   = (const float*)d_in[3];
    const float* Wi     = (const float*)d_in[4];
    const float* Wh     = (const float*)d_in[5];
    const float* b_lstm = (const float*)d_in[6];
    const float* W_lat  = (const float*)d_in[7];
    const float* b_lat  = (const float*)d_in[8];
    float* out = (float*)d_out;

    __half* zx  = (__half*)d_ws;                        // TT*512*2 = 64 MiB
    int*    idx = (int*)((char*)d_ws + (size_t)TT * G4 * 2);   // TT+2 ints
    int*    cnt = idx + (TT + 2);

    zx_kernel<<<TT / ROWS, 512, 0, stream>>>(x, W_in, b_in, Wi, b_lstm, zx);
    compact_kernel<<<1, CTH, 0, stream>>>(mask, idx, cnt);
    scan_kernel<<<1, 256, 0, stream>>>(zx, Wh, idx, cnt, W_lat, b_lat, out);
}